// Round 10
// baseline (347.836 us; speedup 1.0000x reference)
//
#include <hip/hip_runtime.h>
#include <cstddef>

#define D 64
#define RPB 512            // rows per partition bucket (9-bit row_local)
#define MAXB 512           // max bucket count (nb = 293)
#define PCHUNK 4096        // edges per partition block
#define PTHREADS 512       // partition / rowsort block size
#define EPT (PCHUNK / PTHREADS)   // 8 edges per thread
#define TB 64              // head: batch rows per block

// ---- bf16 helpers (round-to-nearest-even) ----------------------------------
static __device__ __forceinline__ unsigned short f2b(float f) {
    unsigned u = __float_as_uint(f);
    return (unsigned short)((u + 0x7FFFu + ((u >> 16) & 1u)) >> 16);
}
static __device__ __forceinline__ float b2f(unsigned short h) {
    return __uint_as_float(((unsigned)h) << 16);
}

// ---------------------------------------------------------------------------
// convert: e0_bf16 = round(concat(emb_user, emb_item))
// ---------------------------------------------------------------------------
__global__ void convert_kernel(const float* __restrict__ eu, const float* __restrict__ ei,
                               unsigned short* __restrict__ e0, int nd_user, int nd_total) {
    int i = blockIdx.x * blockDim.x + threadIdx.x;
    int stride = gridDim.x * blockDim.x;
    int nq = nd_total >> 2, nqu = nd_user >> 2;
    for (int idx = i; idx < nq; idx += stride) {
        float4 v = (idx < nqu) ? ((const float4*)eu)[idx] : ((const float4*)ei)[idx - nqu];
        ushort4 o;
        o.x = f2b(v.x); o.y = f2b(v.y); o.z = f2b(v.z); o.w = f2b(v.w);
        ((ushort4*)e0)[idx] = o;
    }
}

// ---------------------------------------------------------------------------
// mark: flag rows the head will read
// ---------------------------------------------------------------------------
__global__ void mark_kernel(const int* __restrict__ users, const int* __restrict__ items,
                            int* __restrict__ flags, int B, int n_users) {
    int i = blockIdx.x * blockDim.x + threadIdx.x;
    if (i < B) {
        flags[users[i]] = 1;
        flags[n_users + items[i]] = 1;
    }
}

// ---------------------------------------------------------------------------
// bucket_hist: global histogram over row>>9 buckets, LDS-privatized
// ---------------------------------------------------------------------------
__global__ __launch_bounds__(256)
void bucket_hist_kernel(const int* __restrict__ row, int* __restrict__ ghist,
                        int nnz, int nb) {
    __shared__ int h[MAXB];
    for (int b = threadIdx.x; b < nb; b += blockDim.x) h[b] = 0;
    __syncthreads();
    int i = blockIdx.x * blockDim.x + threadIdx.x;
    int stride = gridDim.x * blockDim.x;
    for (int e = i; e < nnz; e += stride) atomicAdd(&h[row[e] >> 9], 1);
    __syncthreads();
    for (int b = threadIdx.x; b < nb; b += blockDim.x)
        if (h[b]) atomicAdd(&ghist[b], h[b]);
}

// ---------------------------------------------------------------------------
// bucket_scan: single-block exclusive scan; writes bofs[0..nb], gcur=bofs
// ---------------------------------------------------------------------------
__global__ __launch_bounds__(256)
void bucket_scan_kernel(const int* __restrict__ ghist, int* __restrict__ bofs,
                        int* __restrict__ gcur, int nb, int nnz) {
    __shared__ int part[256];
    int seg = (nb + 255) >> 8;
    int base = threadIdx.x * seg;
    int s = 0;
    for (int i = 0; i < seg; ++i)
        if (base + i < nb) s += ghist[base + i];
    part[threadIdx.x] = s;
    __syncthreads();
    for (int off = 1; off < 256; off <<= 1) {
        int t = (threadIdx.x >= (unsigned)off) ? part[threadIdx.x - off] : 0;
        __syncthreads();
        part[threadIdx.x] += t;
        __syncthreads();
    }
    int run = part[threadIdx.x] - s;
    for (int i = 0; i < seg; ++i) {
        int b = base + i;
        if (b < nb) {
            bofs[b] = run;
            gcur[b] = run;
            run += ghist[b];
        }
    }
    if (threadIdx.x == 0) bofs[nb] = nnz;
}

// ---------------------------------------------------------------------------
// partition: fused in-LDS counting sort of a 4096-edge chunk by bucket
// (row>>9), then coalesced run writes. key = (row_local9 << 18) | col.
// ---------------------------------------------------------------------------
__global__ __launch_bounds__(PTHREADS)
void partition_kernel(const int* __restrict__ row, const int* __restrict__ col,
                      const float* __restrict__ val, int* __restrict__ gcur,
                      uint2* __restrict__ ep, int nnz, int nb) {
    __shared__ uint2 sorted[PCHUNK];          // 32 KB
    __shared__ unsigned short bid[PCHUNK];    // 8 KB
    __shared__ int hist[MAXB];
    __shared__ int sc[MAXB];
    __shared__ int gofs[MAXB];
    __shared__ int lcur[MAXB];

    int tid  = threadIdx.x;
    int cbeg = blockIdx.x * PCHUNK;
    int cend = min(nnz, cbeg + PCHUNK);
    int cnt  = cend - cbeg;

    for (int b = tid; b < MAXB; b += PTHREADS) hist[b] = 0;
    __syncthreads();

    unsigned mykey[EPT];
    float    myval[EPT];
    int      mybkt[EPT];
    #pragma unroll
    for (int k = 0; k < EPT; ++k) {
        int e = cbeg + k * PTHREADS + tid;
        mybkt[k] = -1;
        if (e < cend) {
            int r = row[e];
            int b = r >> 9;
            mykey[k] = (((unsigned)r & 511u) << 18) | (unsigned)col[e];
            myval[k] = val[e];
            mybkt[k] = b;
            atomicAdd(&hist[b], 1);
        }
    }
    __syncthreads();

    int own = (tid < nb) ? hist[tid] : 0;
    sc[tid] = own;
    __syncthreads();
    for (int off = 1; off < MAXB; off <<= 1) {
        int t = (tid >= off) ? sc[tid - off] : 0;
        __syncthreads();
        sc[tid] += t;
        __syncthreads();
    }
    int excl = sc[tid] - own;
    if (tid < nb) {
        lcur[tid] = excl;
        if (own) gofs[tid] = atomicAdd(&gcur[tid], own) - excl;
    }
    __syncthreads();

    #pragma unroll
    for (int k = 0; k < EPT; ++k) {
        int b = mybkt[k];
        if (b >= 0) {
            int p = atomicAdd(&lcur[b], 1);
            sorted[p] = make_uint2(mykey[k], __float_as_uint(myval[k]));
            bid[p] = (unsigned short)b;
        }
    }
    __syncthreads();

    for (int p = tid; p < cnt; p += PTHREADS)
        ep[p + gofs[bid[p]]] = sorted[p];
}

// ---------------------------------------------------------------------------
// rowsort: per-bucket (512 rows) LDS counting sort into row order; emits ptr.
// ---------------------------------------------------------------------------
__global__ __launch_bounds__(PTHREADS)
void rowsort_kernel(const uint2* __restrict__ ep, const int* __restrict__ bofs,
                    uint2* __restrict__ ep2, int* __restrict__ ptr,
                    int n, int nnz) {
    __shared__ int hist[RPB];
    __shared__ int sc[RPB];
    __shared__ int cur[RPB];
    int b = blockIdx.x;
    int beg = bofs[b], end = bofs[b + 1];
    int tid = threadIdx.x;
    hist[tid] = 0;
    __syncthreads();
    for (int e = beg + tid; e < end; e += PTHREADS)
        atomicAdd(&hist[ep[e].x >> 18], 1);
    __syncthreads();
    int own = hist[tid];
    sc[tid] = own;
    __syncthreads();
    for (int off = 1; off < RPB; off <<= 1) {
        int t = (tid >= off) ? sc[tid - off] : 0;
        __syncthreads();
        sc[tid] += t;
        __syncthreads();
    }
    int excl = sc[tid] - own;
    cur[tid] = excl;
    int r = (b << 9) + tid;
    if (r < n) ptr[r] = beg + excl;
    if (b == 0 && tid == 0) ptr[n] = nnz;
    __syncthreads();
    for (int e = beg + tid; e < end; e += PTHREADS) {
        uint2 kv = ep[e];
        int rl = kv.x >> 18;
        int p = atomicAdd(&cur[rl], 1);
        ep2[beg + p] = kv;
    }
}

// ---------------------------------------------------------------------------
// spmm_bf16: CSR-vector — ONE WAVE PER ROW. Edge stream is wave-uniform
// (readfirstlane -> SGPR, s_load path); lane = dim (ushort gather, 128 B
// coalesced per edge); zero DS ops; f32 accumulate; unroll-4 for MLP.
// ---------------------------------------------------------------------------
__global__ __launch_bounds__(256)
void spmm_bf16_kernel(const int* __restrict__ ptr, const uint2* __restrict__ ep,
                      const unsigned short* __restrict__ x,
                      const int* __restrict__ flags,
                      unsigned short* __restrict__ y, int n) {
    int lane = threadIdx.x & 63;
    int r    = (blockIdx.x * blockDim.x + threadIdx.x) >> 6;
    if (r >= n) return;
    if (flags && !flags[r]) return;

    int beg = __builtin_amdgcn_readfirstlane(ptr[r]);
    int end = __builtin_amdgcn_readfirstlane(ptr[r + 1]);
    const uint2* __restrict__ e = ep + beg;
    const unsigned short* __restrict__ xl = x + lane;
    int deg = end - beg;

    float acc = 0.f;
    int j = 0;
    for (; j + 4 <= deg; j += 4) {
        uint2 k0 = e[j];
        uint2 k1 = e[j + 1];
        uint2 k2 = e[j + 2];
        uint2 k3 = e[j + 3];
        float x0 = b2f(xl[(size_t)(k0.x & 0x3FFFFu) << 6]);
        float x1 = b2f(xl[(size_t)(k1.x & 0x3FFFFu) << 6]);
        float x2 = b2f(xl[(size_t)(k2.x & 0x3FFFFu) << 6]);
        float x3 = b2f(xl[(size_t)(k3.x & 0x3FFFFu) << 6]);
        acc = fmaf(__uint_as_float(k0.y), x0, acc);
        acc = fmaf(__uint_as_float(k1.y), x1, acc);
        acc = fmaf(__uint_as_float(k2.y), x2, acc);
        acc = fmaf(__uint_as_float(k3.y), x3, acc);
    }
    for (; j < deg; ++j) {
        uint2 kv = e[j];
        float xv = b2f(xl[(size_t)(kv.x & 0x3FFFFu) << 6]);
        acc = fmaf(__uint_as_float(kv.y), xv, acc);
    }

    y[((size_t)r << 6) + lane] = f2b(acc);
}

// ---------------------------------------------------------------------------
// head: 64-b tile per block; ue/ie/W transposed in LDS; 4b x 4j patches.
// ---------------------------------------------------------------------------
__global__ __launch_bounds__(256)
void head_kernel(const float* __restrict__ eu, const float* __restrict__ ei,
                 const unsigned short* __restrict__ e1,
                 const unsigned short* __restrict__ e2,
                 const unsigned short* __restrict__ e3,
                 const float* __restrict__ wu, const float* __restrict__ wi,
                 const float* __restrict__ x1, const float* __restrict__ x0,
                 const int* __restrict__ users, const int* __restrict__ items,
                 const int* __restrict__ xij,
                 float* __restrict__ out, int B, int n_users) {
    __shared__ float uet[D * TB];   // [k][b]
    __shared__ float iet[D * TB];
    __shared__ float wut[D * D];    // [k][j] = wu[j][k]
    __shared__ float wit[D * D];

    int t  = threadIdx.x;
    int b0 = blockIdx.x * TB;

    for (int i = t; i < D * D; i += 256) {
        int k = i >> 6, j = i & 63;
        wut[i] = wu[j * D + k];
        wit[i] = wi[j * D + k];
    }

    {
        int l  = t & 15;
        int g  = t >> 4;
        for (int p = 0; p < 4; ++p) {
            int bl = g + p * 16;
            int b  = b0 + bl;
            if (b < B) {
                int u  = users[b];
                int it = items[b];
                size_t uo  = ((size_t)u << 6);
                size_t io  = ((size_t)(n_users + it) << 6);
                size_t io2 = ((size_t)it << 6);
                float4  fu = ((const float4*)(eu + uo))[l];
                ushort4 u1 = ((const ushort4*)(e1 + uo))[l];
                ushort4 u2 = ((const ushort4*)(e2 + uo))[l];
                ushort4 u3 = ((const ushort4*)(e3 + uo))[l];
                float4  fi = ((const float4*)(ei + io2))[l];
                ushort4 i1 = ((const ushort4*)(e1 + io))[l];
                ushort4 i2 = ((const ushort4*)(e2 + io))[l];
                ushort4 i3 = ((const ushort4*)(e3 + io))[l];
                int k0 = l << 2;
                uet[(k0 + 0) * TB + bl] = (fu.x + b2f(u1.x) + b2f(u2.x) + b2f(u3.x)) * 0.25f;
                uet[(k0 + 1) * TB + bl] = (fu.y + b2f(u1.y) + b2f(u2.y) + b2f(u3.y)) * 0.25f;
                uet[(k0 + 2) * TB + bl] = (fu.z + b2f(u1.z) + b2f(u2.z) + b2f(u3.z)) * 0.25f;
                uet[(k0 + 3) * TB + bl] = (fu.w + b2f(u1.w) + b2f(u2.w) + b2f(u3.w)) * 0.25f;
                iet[(k0 + 0) * TB + bl] = (fi.x + b2f(i1.x) + b2f(i2.x) + b2f(i3.x)) * 0.25f;
                iet[(k0 + 1) * TB + bl] = (fi.y + b2f(i1.y) + b2f(i2.y) + b2f(i3.y)) * 0.25f;
                iet[(k0 + 2) * TB + bl] = (fi.z + b2f(i1.z) + b2f(i2.z) + b2f(i3.z)) * 0.25f;
                iet[(k0 + 3) * TB + bl] = (fi.w + b2f(i1.w) + b2f(i2.w) + b2f(i3.w)) * 0.25f;
            }
        }
    }
    __syncthreads();

    int jg = (t & 15) << 2;
    int bg = (t >> 4) << 2;
    float su[4][4], si[4][4];
    #pragma unroll
    for (int a = 0; a < 4; ++a)
        #pragma unroll
        for (int c = 0; c < 4; ++c) { su[a][c] = 0.f; si[a][c] = 0.f; }

    #pragma unroll 4
    for (int k = 0; k < D; ++k) {
        float4 u4 = *(const float4*)&uet[k * TB + bg];
        float4 i4 = *(const float4*)&iet[k * TB + bg];
        float4 a4 = *(const float4*)&wut[k * D + jg];
        float4 c4 = *(const float4*)&wit[k * D + jg];
        const float ub[4] = {u4.x, u4.y, u4.z, u4.w};
        const float ib[4] = {i4.x, i4.y, i4.z, i4.w};
        const float wa[4] = {a4.x, a4.y, a4.z, a4.w};
        const float wc[4] = {c4.x, c4.y, c4.z, c4.w};
        #pragma unroll
        for (int a = 0; a < 4; ++a)
            #pragma unroll
            for (int c = 0; c < 4; ++c) {
                su[a][c] = fmaf(ub[a], wa[c], su[a][c]);
                si[a][c] = fmaf(ib[a], wc[c], si[a][c]);
            }
    }

    float m[4], S[4], T[4];
    #pragma unroll
    for (int a = 0; a < 4; ++a) {
        float mm = fmaxf(fmaxf(su[a][0], su[a][1]), fmaxf(su[a][2], su[a][3]));
        for (int off = 1; off < 16; off <<= 1) mm = fmaxf(mm, __shfl_xor(mm, off));
        m[a] = mm;
    }
    #pragma unroll
    for (int a = 0; a < 4; ++a) {
        float sl = 0.f, tl = 0.f;
        #pragma unroll
        for (int c = 0; c < 4; ++c) {
            float e = __expf(su[a][c] - m[a]);
            float gg = 1.f / (1.f + __expf(-si[a][c]));
            sl += e;
            tl = fmaf(e, gg, tl);
        }
        for (int off = 1; off < 16; off <<= 1) {
            sl += __shfl_xor(sl, off);
            tl += __shfl_xor(tl, off);
        }
        S[a] = sl; T[a] = tl;
    }

    if ((t & 15) == 0) {
        #pragma unroll
        for (int a = 0; a < 4; ++a) {
            int b = b0 + bg + a;
            if (b < B) {
                int it = items[b];
                float xe   = (xij[b] > 0) ? x1[it] : x0[it];
                float sigx = 1.f / (1.f + __expf(-xe));
                out[b] = 0.5f * T[a] / S[a] + 0.5f * sigx;
            }
        }
    }
}

// ---------------------------------------------------------------------------
// fallback path kernels (only if ws too small) — full f32, atomic scatter
// ---------------------------------------------------------------------------
__global__ void init_kernel(const float* __restrict__ eu, const float* __restrict__ ei,
                            float* __restrict__ e_cur, float* __restrict__ acc,
                            int nd_user, int nd_total) {
    int i = blockIdx.x * blockDim.x + threadIdx.x;
    int stride = gridDim.x * blockDim.x;
    int nq = nd_total >> 2;
    int nq_user = nd_user >> 2;
    for (int idx = i; idx < nq; idx += stride) {
        float4 v;
        if (idx < nq_user) v = ((const float4*)eu)[idx];
        else               v = ((const float4*)ei)[idx - nq_user];
        ((float4*)e_cur)[idx] = v;
        ((float4*)acc)[idx]   = v;
    }
}

__global__ void spmm_atomic_kernel(const int* __restrict__ row, const int* __restrict__ col,
                                   const float* __restrict__ val, const float* __restrict__ x,
                                   float* __restrict__ y, int nnz) {
    int lane  = threadIdx.x & 63;
    int wave  = (blockIdx.x * blockDim.x + threadIdx.x) >> 6;
    int nwave = (gridDim.x * blockDim.x) >> 6;
    for (int e = wave; e < nnz; e += nwave)
        atomicAdd(&y[(size_t)row[e] * D + lane], val[e] * x[(size_t)col[e] * D + lane]);
}

__global__ void accum_kernel(float* __restrict__ acc, const float* __restrict__ nxt,
                             int nd_total) {
    int i = blockIdx.x * blockDim.x + threadIdx.x;
    int stride = gridDim.x * blockDim.x;
    int nq = nd_total >> 2;
    for (int idx = i; idx < nq; idx += stride) {
        float4 a = ((float4*)acc)[idx];
        float4 b = ((const float4*)nxt)[idx];
        a.x += b.x; a.y += b.y; a.z += b.z; a.w += b.w;
        ((float4*)acc)[idx] = a;
    }
}

__global__ __launch_bounds__(256)
void head_acc_kernel(const float* __restrict__ acc,
                     const float* __restrict__ wu, const float* __restrict__ wi,
                     const float* __restrict__ x1, const float* __restrict__ x0,
                     const int* __restrict__ users, const int* __restrict__ items,
                     const int* __restrict__ xij,
                     float* __restrict__ out, int B, int n_users) {
    __shared__ float wtu[D * D];
    __shared__ float wti[D * D];
    for (int idx = threadIdx.x; idx < D * D; idx += blockDim.x) {
        int j = idx >> 6, k = idx & 63;
        wtu[k * D + j] = wu[idx];
        wti[k * D + j] = wi[idx];
    }
    __syncthreads();
    int lane = threadIdx.x & 63;
    int wid  = threadIdx.x >> 6;
    int nw   = blockDim.x >> 6;
    for (int b = blockIdx.x * nw + wid; b < B; b += gridDim.x * nw) {
        int u  = users[b];
        int it = items[b];
        float ue = acc[(size_t)u * D + lane] * 0.25f;
        float ie = acc[(size_t)(n_users + it) * D + lane] * 0.25f;
        float su = 0.f, si = 0.f;
        #pragma unroll 8
        for (int k = 0; k < D; ++k) {
            float uk = __shfl(ue, k);
            float ik = __shfl(ie, k);
            su = fmaf(uk, wtu[k * D + lane], su);
            si = fmaf(ik, wti[k * D + lane], si);
        }
        float m = su;
        for (int off = 32; off > 0; off >>= 1) m = fmaxf(m, __shfl_xor(m, off));
        float p = __expf(su - m);
        float sden = p;
        for (int off = 32; off > 0; off >>= 1) sden += __shfl_xor(sden, off);
        float soft = p / sden;
        float sig  = 1.f / (1.f + __expf(-si));
        float term = 0.5f * soft * sig;
        for (int off = 32; off > 0; off >>= 1) term += __shfl_xor(term, off);
        if (lane == 0) {
            float xe   = (xij[b] > 0) ? x1[it] : x0[it];
            float sigx = 1.f / (1.f + __expf(-xe));
            out[b] = term + 0.5f * sigx;
        }
    }
}

// ---------------------------------------------------------------------------
extern "C" void kernel_launch(void* const* d_in, const int* in_sizes, int n_in,
                              void* d_out, int out_size, void* d_ws, size_t ws_size,
                              hipStream_t stream) {
    const float* emb_user = (const float*)d_in[0];
    const float* emb_item = (const float*)d_in[1];
    const float* w_user   = (const float*)d_in[2];
    const float* w_item   = (const float*)d_in[3];
    const float* xij_emb1 = (const float*)d_in[4];
    const float* xij_emb0 = (const float*)d_in[5];
    const float* g_val    = (const float*)d_in[6];
    const int*   g_row    = (const int*)d_in[7];
    const int*   g_col    = (const int*)d_in[8];
    const int*   users    = (const int*)d_in[9];
    const int*   items    = (const int*)d_in[10];
    const int*   xij      = (const int*)d_in[11];
    float*       out      = (float*)d_out;

    const int n_users = in_sizes[0] / D;     // 100000
    const int n_items = in_sizes[1] / D;     // 50000
    const int n_total = n_users + n_items;   // 150000
    const int nnz     = in_sizes[6];         // 2000000
    const int B       = in_sizes[9];         // 16384

    const int nd_user  = n_users * D;
    const int nd_total = n_total * D;
    const int nb = (n_total + RPB - 1) / RPB;                 // 293

    const size_t hbytes   = (((size_t)nd_total * 2) + 255) & ~(size_t)255;
    const size_t ebytes   = (size_t)nnz * sizeof(uint2);
    const size_t ptrbytes = ((size_t)(n_total + 1) * 4 + 255) & ~(size_t)255;
    const size_t flbytes  = ((size_t)n_total * 4 + 255) & ~(size_t)255;
    const size_t ibytes   = ((size_t)(nb + 1) * 4 + 255) & ~(size_t)255;
    const size_t need = 4 * hbytes + 2 * ebytes + ptrbytes + flbytes + 3 * ibytes + 256;

    if (ws_size >= need && nb <= MAXB) {
        char* w = (char*)d_ws;
        unsigned short* e0 = (unsigned short*)w;  w += hbytes;
        unsigned short* e1 = (unsigned short*)w;  w += hbytes;
        unsigned short* e2 = (unsigned short*)w;  w += hbytes;
        unsigned short* e3 = (unsigned short*)w;  w += hbytes;
        uint2* ep    = (uint2*)w;                 w += ebytes;
        uint2* ep2   = (uint2*)w;                 w += ebytes;
        int*   ptr   = (int*)w;                   w += ptrbytes;
        int*   flags = (int*)w;                   w += flbytes;
        int*   ghist = (int*)w;                   w += ibytes;
        int*   bofs  = (int*)w;                   w += ibytes;
        int*   gcur  = (int*)w;                   w += ibytes;

        hipMemsetAsync(ghist, 0, (size_t)nb * 4, stream);
        hipMemsetAsync(flags, 0, (size_t)n_total * 4, stream);

        convert_kernel<<<2048, 256, 0, stream>>>(emb_user, emb_item, e0,
                                                 nd_user, nd_total);
        mark_kernel<<<(B + 255) / 256, 256, 0, stream>>>(users, items, flags,
                                                         B, n_users);

        bucket_hist_kernel<<<256, 256, 0, stream>>>(g_row, ghist, nnz, nb);
        bucket_scan_kernel<<<1, 256, 0, stream>>>(ghist, bofs, gcur, nb, nnz);
        const int pblocks = (nnz + PCHUNK - 1) / PCHUNK;
        partition_kernel<<<pblocks, PTHREADS, 0, stream>>>(g_row, g_col, g_val, gcur,
                                                           ep, nnz, nb);
        rowsort_kernel<<<nb, PTHREADS, 0, stream>>>(ep, bofs, ep2, ptr, n_total, nnz);

        const int nblk = (n_total * 64 + 255) / 256;   // one wave per row
        spmm_bf16_kernel<<<nblk, 256, 0, stream>>>(ptr, ep2, e0, nullptr, e1, n_total);
        spmm_bf16_kernel<<<nblk, 256, 0, stream>>>(ptr, ep2, e1, nullptr, e2, n_total);
        spmm_bf16_kernel<<<nblk, 256, 0, stream>>>(ptr, ep2, e2, flags,  e3, n_total);

        head_kernel<<<(B + TB - 1) / TB, 256, 0, stream>>>(
            emb_user, emb_item, e1, e2, e3,
            w_user, w_item, xij_emb1, xij_emb0,
            users, items, xij, out, B, n_users);
    } else {
        const size_t fbytes = (size_t)nd_total * sizeof(float);
        char* w = (char*)d_ws;
        float* e_a = (float*)w;  w += fbytes;
        float* e_b = (float*)w;  w += fbytes;
        float* acc = (float*)w;  w += fbytes;
        float* cur = e_a;
        float* nxt = e_b;
        init_kernel<<<2048, 256, 0, stream>>>(emb_user, emb_item, cur, acc,
                                              nd_user, nd_total);
        for (int l = 0; l < 3; ++l) {
            hipMemsetAsync(nxt, 0, fbytes, stream);
            spmm_atomic_kernel<<<2048, 256, 0, stream>>>(g_row, g_col, g_val, cur, nxt, nnz);
            accum_kernel<<<2048, 256, 0, stream>>>(acc, nxt, nd_total);
            float* t = cur; cur = nxt; nxt = t;
        }
        head_acc_kernel<<<256, 256, 0, stream>>>(acc, w_user, w_item,
                                                 xij_emb1, xij_emb0,
                                                 users, items, xij, out, B, n_users);
    }
}

// Round 11
// 292.034 us; speedup vs baseline: 1.1911x; 1.1911x over previous
//
#include <hip/hip_runtime.h>
#include <cstddef>

#define D 64
#define RPB 512            // rows per partition bucket (9-bit row_local)
#define MAXB 512           // max bucket count (nb = 293)
#define PCHUNK 4096        // edges per partition block
#define PTHREADS 512       // partition / rowsort block size
#define EPT (PCHUNK / PTHREADS)   // 8 edges per thread
#define TB 64              // head: batch rows per block

// ---- bf16 helpers (round-to-nearest-even) ----------------------------------
static __device__ __forceinline__ unsigned short f2b(float f) {
    unsigned u = __float_as_uint(f);
    return (unsigned short)((u + 0x7FFFu + ((u >> 16) & 1u)) >> 16);
}
static __device__ __forceinline__ float b2f(unsigned short h) {
    return __uint_as_float(((unsigned)h) << 16);
}

// ---------------------------------------------------------------------------
// convert: e0_bf16 = round(concat(emb_user, emb_item)); also marks head rows
// ---------------------------------------------------------------------------
__global__ void convert_kernel(const float* __restrict__ eu, const float* __restrict__ ei,
                               unsigned short* __restrict__ e0, int nd_user, int nd_total,
                               const int* __restrict__ users, const int* __restrict__ items,
                               int* __restrict__ flags, int B, int n_users) {
    int i = blockIdx.x * blockDim.x + threadIdx.x;
    int stride = gridDim.x * blockDim.x;
    if (i < B) {                       // fused mark (flags pre-zeroed)
        flags[users[i]] = 1;
        flags[n_users + items[i]] = 1;
    }
    int nq = nd_total >> 2, nqu = nd_user >> 2;
    for (int idx = i; idx < nq; idx += stride) {
        float4 v = (idx < nqu) ? ((const float4*)eu)[idx] : ((const float4*)ei)[idx - nqu];
        ushort4 o;
        o.x = f2b(v.x); o.y = f2b(v.y); o.z = f2b(v.z); o.w = f2b(v.w);
        ((ushort4*)e0)[idx] = o;
    }
}

// ---------------------------------------------------------------------------
// bucket_hist: global histogram over row>>9 buckets, LDS-privatized
// ---------------------------------------------------------------------------
__global__ __launch_bounds__(256)
void bucket_hist_kernel(const int* __restrict__ row, int* __restrict__ ghist,
                        int nnz, int nb) {
    __shared__ int h[MAXB];
    for (int b = threadIdx.x; b < nb; b += blockDim.x) h[b] = 0;
    __syncthreads();
    int i = blockIdx.x * blockDim.x + threadIdx.x;
    int stride = gridDim.x * blockDim.x;
    for (int e = i; e < nnz; e += stride) atomicAdd(&h[row[e] >> 9], 1);
    __syncthreads();
    for (int b = threadIdx.x; b < nb; b += blockDim.x)
        if (h[b]) atomicAdd(&ghist[b], h[b]);
}

// ---------------------------------------------------------------------------
// bucket_scan: single-block exclusive scan; writes bofs[0..nb], gcur=bofs
// ---------------------------------------------------------------------------
__global__ __launch_bounds__(256)
void bucket_scan_kernel(const int* __restrict__ ghist, int* __restrict__ bofs,
                        int* __restrict__ gcur, int nb, int nnz) {
    __shared__ int part[256];
    int seg = (nb + 255) >> 8;
    int base = threadIdx.x * seg;
    int s = 0;
    for (int i = 0; i < seg; ++i)
        if (base + i < nb) s += ghist[base + i];
    part[threadIdx.x] = s;
    __syncthreads();
    for (int off = 1; off < 256; off <<= 1) {
        int t = (threadIdx.x >= (unsigned)off) ? part[threadIdx.x - off] : 0;
        __syncthreads();
        part[threadIdx.x] += t;
        __syncthreads();
    }
    int run = part[threadIdx.x] - s;
    for (int i = 0; i < seg; ++i) {
        int b = base + i;
        if (b < nb) {
            bofs[b] = run;
            gcur[b] = run;
            run += ghist[b];
        }
    }
    if (threadIdx.x == 0) bofs[nb] = nnz;
}

// ---------------------------------------------------------------------------
// partition: fused in-LDS counting sort of a 4096-edge chunk by bucket
// (row>>9), then coalesced run writes. key = (row_local9 << 18) | col.
// ---------------------------------------------------------------------------
__global__ __launch_bounds__(PTHREADS)
void partition_kernel(const int* __restrict__ row, const int* __restrict__ col,
                      const float* __restrict__ val, int* __restrict__ gcur,
                      uint2* __restrict__ ep, int nnz, int nb) {
    __shared__ uint2 sorted[PCHUNK];          // 32 KB
    __shared__ unsigned short bid[PCHUNK];    // 8 KB
    __shared__ int hist[MAXB];
    __shared__ int sc[MAXB];
    __shared__ int gofs[MAXB];
    __shared__ int lcur[MAXB];

    int tid  = threadIdx.x;
    int cbeg = blockIdx.x * PCHUNK;
    int cend = min(nnz, cbeg + PCHUNK);
    int cnt  = cend - cbeg;

    for (int b = tid; b < MAXB; b += PTHREADS) hist[b] = 0;
    __syncthreads();

    unsigned mykey[EPT];
    float    myval[EPT];
    int      mybkt[EPT];
    #pragma unroll
    for (int k = 0; k < EPT; ++k) {
        int e = cbeg + k * PTHREADS + tid;
        mybkt[k] = -1;
        if (e < cend) {
            int r = row[e];
            int b = r >> 9;
            mykey[k] = (((unsigned)r & 511u) << 18) | (unsigned)col[e];
            myval[k] = val[e];
            mybkt[k] = b;
            atomicAdd(&hist[b], 1);
        }
    }
    __syncthreads();

    int own = (tid < nb) ? hist[tid] : 0;
    sc[tid] = own;
    __syncthreads();
    for (int off = 1; off < MAXB; off <<= 1) {
        int t = (tid >= off) ? sc[tid - off] : 0;
        __syncthreads();
        sc[tid] += t;
        __syncthreads();
    }
    int excl = sc[tid] - own;
    if (tid < nb) {
        lcur[tid] = excl;
        if (own) gofs[tid] = atomicAdd(&gcur[tid], own) - excl;
    }
    __syncthreads();

    #pragma unroll
    for (int k = 0; k < EPT; ++k) {
        int b = mybkt[k];
        if (b >= 0) {
            int p = atomicAdd(&lcur[b], 1);
            sorted[p] = make_uint2(mykey[k], __float_as_uint(myval[k]));
            bid[p] = (unsigned short)b;
        }
    }
    __syncthreads();

    for (int p = tid; p < cnt; p += PTHREADS)
        ep[p + gofs[bid[p]]] = sorted[p];
}

// ---------------------------------------------------------------------------
// rowsort: per-bucket (512 rows) LDS counting sort into row order; emits ptr.
// ---------------------------------------------------------------------------
__global__ __launch_bounds__(PTHREADS)
void rowsort_kernel(const uint2* __restrict__ ep, const int* __restrict__ bofs,
                    uint2* __restrict__ ep2, int* __restrict__ ptr,
                    int n, int nnz) {
    __shared__ int hist[RPB];
    __shared__ int sc[RPB];
    __shared__ int cur[RPB];
    int b = blockIdx.x;
    int beg = bofs[b], end = bofs[b + 1];
    int tid = threadIdx.x;
    hist[tid] = 0;
    __syncthreads();
    for (int e = beg + tid; e < end; e += PTHREADS)
        atomicAdd(&hist[ep[e].x >> 18], 1);
    __syncthreads();
    int own = hist[tid];
    sc[tid] = own;
    __syncthreads();
    for (int off = 1; off < RPB; off <<= 1) {
        int t = (tid >= off) ? sc[tid - off] : 0;
        __syncthreads();
        sc[tid] += t;
        __syncthreads();
    }
    int excl = sc[tid] - own;
    cur[tid] = excl;
    int r = (b << 9) + tid;
    if (r < n) ptr[r] = beg + excl;
    if (b == 0 && tid == 0) ptr[n] = nnz;
    __syncthreads();
    for (int e = beg + tid; e < end; e += PTHREADS) {
        uint2 kv = ep[e];
        int rl = kv.x >> 18;
        int p = atomicAdd(&cur[rl], 1);
        ep2[beg + p] = kv;
    }
}

// ---------------------------------------------------------------------------
// spmm_bf16 (R7 structure — measured best): 4 rows/wave, 16 lanes/row;
// 16-edge coop preload + shfl broadcast; quad unroll (matches deg~13);
// x,y bf16, f32 accumulate.
// ---------------------------------------------------------------------------
__global__ __launch_bounds__(256)
void spmm_bf16_kernel(const int* __restrict__ ptr, const uint2* __restrict__ ep,
                      const unsigned short* __restrict__ x,
                      const int* __restrict__ flags,
                      unsigned short* __restrict__ y, int n) {
    int lane = threadIdx.x & 63;
    int wid  = (blockIdx.x * blockDim.x + threadIdx.x) >> 6;
    int sub  = lane & 15;
    int rg   = lane >> 4;
    int r    = wid * 4 + rg;
    if (r >= n) return;
    if (flags && !flags[r]) return;

    int beg = ptr[r], end = ptr[r + 1];
    int klbase = lane & 48;
    float4 s = make_float4(0.f, 0.f, 0.f, 0.f);

    for (int base = beg; base < end; base += 16) {
        int m = min(16, end - base);
        uint2 kv = (sub < m) ? ep[base + sub] : make_uint2(0u, 0u);
        int   myc = kv.x & 0x3FFFF;
        float myv = __uint_as_float(kv.y);
        int k = 0;
        for (; k + 4 <= m; k += 4) {
            int   c0 = __shfl(myc, klbase + k);
            int   c1 = __shfl(myc, klbase + k + 1);
            int   c2 = __shfl(myc, klbase + k + 2);
            int   c3 = __shfl(myc, klbase + k + 3);
            float v0 = __shfl(myv, klbase + k);
            float v1 = __shfl(myv, klbase + k + 1);
            float v2 = __shfl(myv, klbase + k + 2);
            float v3 = __shfl(myv, klbase + k + 3);
            ushort4 h0 = ((const ushort4*)(x + ((size_t)c0 << 6)))[sub];
            ushort4 h1 = ((const ushort4*)(x + ((size_t)c1 << 6)))[sub];
            ushort4 h2 = ((const ushort4*)(x + ((size_t)c2 << 6)))[sub];
            ushort4 h3 = ((const ushort4*)(x + ((size_t)c3 << 6)))[sub];
            s.x = fmaf(v0, b2f(h0.x), s.x); s.y = fmaf(v0, b2f(h0.y), s.y);
            s.z = fmaf(v0, b2f(h0.z), s.z); s.w = fmaf(v0, b2f(h0.w), s.w);
            s.x = fmaf(v1, b2f(h1.x), s.x); s.y = fmaf(v1, b2f(h1.y), s.y);
            s.z = fmaf(v1, b2f(h1.z), s.z); s.w = fmaf(v1, b2f(h1.w), s.w);
            s.x = fmaf(v2, b2f(h2.x), s.x); s.y = fmaf(v2, b2f(h2.y), s.y);
            s.z = fmaf(v2, b2f(h2.z), s.z); s.w = fmaf(v2, b2f(h2.w), s.w);
            s.x = fmaf(v3, b2f(h3.x), s.x); s.y = fmaf(v3, b2f(h3.y), s.y);
            s.z = fmaf(v3, b2f(h3.z), s.z); s.w = fmaf(v3, b2f(h3.w), s.w);
        }
        for (; k < m; ++k) {
            int   c = __shfl(myc, klbase + k);
            float v = __shfl(myv, klbase + k);
            ushort4 h = ((const ushort4*)(x + ((size_t)c << 6)))[sub];
            s.x = fmaf(v, b2f(h.x), s.x); s.y = fmaf(v, b2f(h.y), s.y);
            s.z = fmaf(v, b2f(h.z), s.z); s.w = fmaf(v, b2f(h.w), s.w);
        }
    }

    ushort4 o;
    o.x = f2b(s.x); o.y = f2b(s.y); o.z = f2b(s.z); o.w = f2b(s.w);
    ((ushort4*)(y + ((size_t)r << 6)))[sub] = o;
}

// ---------------------------------------------------------------------------
// head: 64-b tile per block; ue/ie/W transposed in LDS; 4b x 4j patches.
// ---------------------------------------------------------------------------
__global__ __launch_bounds__(256)
void head_kernel(const float* __restrict__ eu, const float* __restrict__ ei,
                 const unsigned short* __restrict__ e1,
                 const unsigned short* __restrict__ e2,
                 const unsigned short* __restrict__ e3,
                 const float* __restrict__ wu, const float* __restrict__ wi,
                 const float* __restrict__ x1, const float* __restrict__ x0,
                 const int* __restrict__ users, const int* __restrict__ items,
                 const int* __restrict__ xij,
                 float* __restrict__ out, int B, int n_users) {
    __shared__ float uet[D * TB];   // [k][b]
    __shared__ float iet[D * TB];
    __shared__ float wut[D * D];    // [k][j] = wu[j][k]
    __shared__ float wit[D * D];

    int t  = threadIdx.x;
    int b0 = blockIdx.x * TB;

    for (int i = t; i < D * D; i += 256) {
        int k = i >> 6, j = i & 63;
        wut[i] = wu[j * D + k];
        wit[i] = wi[j * D + k];
    }

    {
        int l  = t & 15;
        int g  = t >> 4;
        for (int p = 0; p < 4; ++p) {
            int bl = g + p * 16;
            int b  = b0 + bl;
            if (b < B) {
                int u  = users[b];
                int it = items[b];
                size_t uo  = ((size_t)u << 6);
                size_t io  = ((size_t)(n_users + it) << 6);
                size_t io2 = ((size_t)it << 6);
                float4  fu = ((const float4*)(eu + uo))[l];
                ushort4 u1 = ((const ushort4*)(e1 + uo))[l];
                ushort4 u2 = ((const ushort4*)(e2 + uo))[l];
                ushort4 u3 = ((const ushort4*)(e3 + uo))[l];
                float4  fi = ((const float4*)(ei + io2))[l];
                ushort4 i1 = ((const ushort4*)(e1 + io))[l];
                ushort4 i2 = ((const ushort4*)(e2 + io))[l];
                ushort4 i3 = ((const ushort4*)(e3 + io))[l];
                int k0 = l << 2;
                uet[(k0 + 0) * TB + bl] = (fu.x + b2f(u1.x) + b2f(u2.x) + b2f(u3.x)) * 0.25f;
                uet[(k0 + 1) * TB + bl] = (fu.y + b2f(u1.y) + b2f(u2.y) + b2f(u3.y)) * 0.25f;
                uet[(k0 + 2) * TB + bl] = (fu.z + b2f(u1.z) + b2f(u2.z) + b2f(u3.z)) * 0.25f;
                uet[(k0 + 3) * TB + bl] = (fu.w + b2f(u1.w) + b2f(u2.w) + b2f(u3.w)) * 0.25f;
                iet[(k0 + 0) * TB + bl] = (fi.x + b2f(i1.x) + b2f(i2.x) + b2f(i3.x)) * 0.25f;
                iet[(k0 + 1) * TB + bl] = (fi.y + b2f(i1.y) + b2f(i2.y) + b2f(i3.y)) * 0.25f;
                iet[(k0 + 2) * TB + bl] = (fi.z + b2f(i1.z) + b2f(i2.z) + b2f(i3.z)) * 0.25f;
                iet[(k0 + 3) * TB + bl] = (fi.w + b2f(i1.w) + b2f(i2.w) + b2f(i3.w)) * 0.25f;
            }
        }
    }
    __syncthreads();

    int jg = (t & 15) << 2;
    int bg = (t >> 4) << 2;
    float su[4][4], si[4][4];
    #pragma unroll
    for (int a = 0; a < 4; ++a)
        #pragma unroll
        for (int c = 0; c < 4; ++c) { su[a][c] = 0.f; si[a][c] = 0.f; }

    #pragma unroll 4
    for (int k = 0; k < D; ++k) {
        float4 u4 = *(const float4*)&uet[k * TB + bg];
        float4 i4 = *(const float4*)&iet[k * TB + bg];
        float4 a4 = *(const float4*)&wut[k * D + jg];
        float4 c4 = *(const float4*)&wit[k * D + jg];
        const float ub[4] = {u4.x, u4.y, u4.z, u4.w};
        const float ib[4] = {i4.x, i4.y, i4.z, i4.w};
        const float wa[4] = {a4.x, a4.y, a4.z, a4.w};
        const float wc[4] = {c4.x, c4.y, c4.z, c4.w};
        #pragma unroll
        for (int a = 0; a < 4; ++a)
            #pragma unroll
            for (int c = 0; c < 4; ++c) {
                su[a][c] = fmaf(ub[a], wa[c], su[a][c]);
                si[a][c] = fmaf(ib[a], wc[c], si[a][c]);
            }
    }

    float m[4], S[4], T[4];
    #pragma unroll
    for (int a = 0; a < 4; ++a) {
        float mm = fmaxf(fmaxf(su[a][0], su[a][1]), fmaxf(su[a][2], su[a][3]));
        for (int off = 1; off < 16; off <<= 1) mm = fmaxf(mm, __shfl_xor(mm, off));
        m[a] = mm;
    }
    #pragma unroll
    for (int a = 0; a < 4; ++a) {
        float sl = 0.f, tl = 0.f;
        #pragma unroll
        for (int c = 0; c < 4; ++c) {
            float e = __expf(su[a][c] - m[a]);
            float gg = 1.f / (1.f + __expf(-si[a][c]));
            sl += e;
            tl = fmaf(e, gg, tl);
        }
        for (int off = 1; off < 16; off <<= 1) {
            sl += __shfl_xor(sl, off);
            tl += __shfl_xor(tl, off);
        }
        S[a] = sl; T[a] = tl;
    }

    if ((t & 15) == 0) {
        #pragma unroll
        for (int a = 0; a < 4; ++a) {
            int b = b0 + bg + a;
            if (b < B) {
                int it = items[b];
                float xe   = (xij[b] > 0) ? x1[it] : x0[it];
                float sigx = 1.f / (1.f + __expf(-xe));
                out[b] = 0.5f * T[a] / S[a] + 0.5f * sigx;
            }
        }
    }
}

// ---------------------------------------------------------------------------
// fallback path kernels (only if ws too small) — full f32, atomic scatter
// ---------------------------------------------------------------------------
__global__ void init_kernel(const float* __restrict__ eu, const float* __restrict__ ei,
                            float* __restrict__ e_cur, float* __restrict__ acc,
                            int nd_user, int nd_total) {
    int i = blockIdx.x * blockDim.x + threadIdx.x;
    int stride = gridDim.x * blockDim.x;
    int nq = nd_total >> 2;
    int nq_user = nd_user >> 2;
    for (int idx = i; idx < nq; idx += stride) {
        float4 v;
        if (idx < nq_user) v = ((const float4*)eu)[idx];
        else               v = ((const float4*)ei)[idx - nq_user];
        ((float4*)e_cur)[idx] = v;
        ((float4*)acc)[idx]   = v;
    }
}

__global__ void spmm_atomic_kernel(const int* __restrict__ row, const int* __restrict__ col,
                                   const float* __restrict__ val, const float* __restrict__ x,
                                   float* __restrict__ y, int nnz) {
    int lane  = threadIdx.x & 63;
    int wave  = (blockIdx.x * blockDim.x + threadIdx.x) >> 6;
    int nwave = (gridDim.x * blockDim.x) >> 6;
    for (int e = wave; e < nnz; e += nwave)
        atomicAdd(&y[(size_t)row[e] * D + lane], val[e] * x[(size_t)col[e] * D + lane]);
}

__global__ void accum_kernel(float* __restrict__ acc, const float* __restrict__ nxt,
                             int nd_total) {
    int i = blockIdx.x * blockDim.x + threadIdx.x;
    int stride = gridDim.x * blockDim.x;
    int nq = nd_total >> 2;
    for (int idx = i; idx < nq; idx += stride) {
        float4 a = ((float4*)acc)[idx];
        float4 b = ((const float4*)nxt)[idx];
        a.x += b.x; a.y += b.y; a.z += b.z; a.w += b.w;
        ((float4*)acc)[idx] = a;
    }
}

__global__ __launch_bounds__(256)
void head_acc_kernel(const float* __restrict__ acc,
                     const float* __restrict__ wu, const float* __restrict__ wi,
                     const float* __restrict__ x1, const float* __restrict__ x0,
                     const int* __restrict__ users, const int* __restrict__ items,
                     const int* __restrict__ xij,
                     float* __restrict__ out, int B, int n_users) {
    __shared__ float wtu[D * D];
    __shared__ float wti[D * D];
    for (int idx = threadIdx.x; idx < D * D; idx += blockDim.x) {
        int j = idx >> 6, k = idx & 63;
        wtu[k * D + j] = wu[idx];
        wti[k * D + j] = wi[idx];
    }
    __syncthreads();
    int lane = threadIdx.x & 63;
    int wid  = threadIdx.x >> 6;
    int nw   = blockDim.x >> 6;
    for (int b = blockIdx.x * nw + wid; b < B; b += gridDim.x * nw) {
        int u  = users[b];
        int it = items[b];
        float ue = acc[(size_t)u * D + lane] * 0.25f;
        float ie = acc[(size_t)(n_users + it) * D + lane] * 0.25f;
        float su = 0.f, si = 0.f;
        #pragma unroll 8
        for (int k = 0; k < D; ++k) {
            float uk = __shfl(ue, k);
            float ik = __shfl(ie, k);
            su = fmaf(uk, wtu[k * D + lane], su);
            si = fmaf(ik, wti[k * D + lane], si);
        }
        float m = su;
        for (int off = 32; off > 0; off >>= 1) m = fmaxf(m, __shfl_xor(m, off));
        float p = __expf(su - m);
        float sden = p;
        for (int off = 32; off > 0; off >>= 1) sden += __shfl_xor(sden, off);
        float soft = p / sden;
        float sig  = 1.f / (1.f + __expf(-si));
        float term = 0.5f * soft * sig;
        for (int off = 32; off > 0; off >>= 1) term += __shfl_xor(term, off);
        if (lane == 0) {
            float xe   = (xij[b] > 0) ? x1[it] : x0[it];
            float sigx = 1.f / (1.f + __expf(-xe));
            out[b] = term + 0.5f * sigx;
        }
    }
}

// ---------------------------------------------------------------------------
extern "C" void kernel_launch(void* const* d_in, const int* in_sizes, int n_in,
                              void* d_out, int out_size, void* d_ws, size_t ws_size,
                              hipStream_t stream) {
    const float* emb_user = (const float*)d_in[0];
    const float* emb_item = (const float*)d_in[1];
    const float* w_user   = (const float*)d_in[2];
    const float* w_item   = (const float*)d_in[3];
    const float* xij_emb1 = (const float*)d_in[4];
    const float* xij_emb0 = (const float*)d_in[5];
    const float* g_val    = (const float*)d_in[6];
    const int*   g_row    = (const int*)d_in[7];
    const int*   g_col    = (const int*)d_in[8];
    const int*   users    = (const int*)d_in[9];
    const int*   items    = (const int*)d_in[10];
    const int*   xij      = (const int*)d_in[11];
    float*       out      = (float*)d_out;

    const int n_users = in_sizes[0] / D;     // 100000
    const int n_items = in_sizes[1] / D;     // 50000
    const int n_total = n_users + n_items;   // 150000
    const int nnz     = in_sizes[6];         // 2000000
    const int B       = in_sizes[9];         // 16384

    const int nd_user  = n_users * D;
    const int nd_total = n_total * D;
    const int nb = (n_total + RPB - 1) / RPB;                 // 293

    const size_t hbytes   = (((size_t)nd_total * 2) + 255) & ~(size_t)255;
    const size_t ebytes   = (size_t)nnz * sizeof(uint2);
    const size_t ptrbytes = ((size_t)(n_total + 1) * 4 + 255) & ~(size_t)255;
    const size_t flbytes  = ((size_t)n_total * 4 + 255) & ~(size_t)255;
    const size_t ibytes   = ((size_t)(nb + 1) * 4 + 255) & ~(size_t)255;
    const size_t need = 4 * hbytes + 2 * ebytes + ptrbytes + flbytes + 3 * ibytes + 256;

    if (ws_size >= need && nb <= MAXB) {
        char* w = (char*)d_ws;
        unsigned short* e0 = (unsigned short*)w;  w += hbytes;
        unsigned short* e1 = (unsigned short*)w;  w += hbytes;
        unsigned short* e2 = (unsigned short*)w;  w += hbytes;
        unsigned short* e3 = (unsigned short*)w;  w += hbytes;
        uint2* ep    = (uint2*)w;                 w += ebytes;
        uint2* ep2   = (uint2*)w;                 w += ebytes;
        int*   ptr   = (int*)w;                   w += ptrbytes;
        int*   flags = (int*)w;                   w += flbytes;
        int*   ghist = (int*)w;                   w += ibytes;
        int*   bofs  = (int*)w;                   w += ibytes;
        int*   gcur  = (int*)w;                   w += ibytes;

        hipMemsetAsync(ghist, 0, (size_t)nb * 4, stream);
        hipMemsetAsync(flags, 0, (size_t)n_total * 4, stream);

        convert_kernel<<<2048, 256, 0, stream>>>(emb_user, emb_item, e0,
                                                 nd_user, nd_total,
                                                 users, items, flags, B, n_users);

        bucket_hist_kernel<<<256, 256, 0, stream>>>(g_row, ghist, nnz, nb);
        bucket_scan_kernel<<<1, 256, 0, stream>>>(ghist, bofs, gcur, nb, nnz);
        const int pblocks = (nnz + PCHUNK - 1) / PCHUNK;
        partition_kernel<<<pblocks, PTHREADS, 0, stream>>>(g_row, g_col, g_val, gcur,
                                                           ep, nnz, nb);
        rowsort_kernel<<<nb, PTHREADS, 0, stream>>>(ep, bofs, ep2, ptr, n_total, nnz);

        const int nblk = (n_total * 16 + 255) / 256;   // 4 rows per wave
        spmm_bf16_kernel<<<nblk, 256, 0, stream>>>(ptr, ep2, e0, nullptr, e1, n_total);
        spmm_bf16_kernel<<<nblk, 256, 0, stream>>>(ptr, ep2, e1, nullptr, e2, n_total);
        spmm_bf16_kernel<<<nblk, 256, 0, stream>>>(ptr, ep2, e2, flags,  e3, n_total);

        head_kernel<<<(B + TB - 1) / TB, 256, 0, stream>>>(
            emb_user, emb_item, e1, e2, e3,
            w_user, w_item, xij_emb1, xij_emb0,
            users, items, xij, out, B, n_users);
    } else {
        const size_t fbytes = (size_t)nd_total * sizeof(float);
        char* w = (char*)d_ws;
        float* e_a = (float*)w;  w += fbytes;
        float* e_b = (float*)w;  w += fbytes;
        float* acc = (float*)w;  w += fbytes;
        float* cur = e_a;
        float* nxt = e_b;
        init_kernel<<<2048, 256, 0, stream>>>(emb_user, emb_item, cur, acc,
                                              nd_user, nd_total);
        for (int l = 0; l < 3; ++l) {
            hipMemsetAsync(nxt, 0, fbytes, stream);
            spmm_atomic_kernel<<<2048, 256, 0, stream>>>(g_row, g_col, g_val, cur, nxt, nnz);
            accum_kernel<<<2048, 256, 0, stream>>>(acc, nxt, nd_total);
            float* t = cur; cur = nxt; nxt = t;
        }
        head_acc_kernel<<<256, 256, 0, stream>>>(acc, w_user, w_item,
                                                 xij_emb1, xij_emb0,
                                                 users, items, xij, out, B, n_users);
    }
}